// Round 7
// baseline (293.549 us; speedup 1.0000x reference)
//
#include <hip/hip_runtime.h>

#define MAX_O 16
#define RPB 256      // rows per block in the loss kernel (== blockDim.x)
#define MATCH_GX 32  // prior-chunk blocks per batch in the match kernel

// ---------------- device helpers ----------------

// balanced_l1: R_ALPHA=0.5, R_GAMMA=1.5, R_BETA=0.11, b = e^3 - 1
__device__ __forceinline__ float bl1f(float diff) {
  const float bc = 19.085537f;  // float32(e^3 - 1)
  float d = fabsf(diff);
  if (d < 0.11f) {
    return 0.5f / bc * (bc * d + 1.0f) * __logf(1.0f + bc * d / 0.11f) - 0.5f * d;
  }
  return 1.5f * d + 1.5f / bc - 0.5f * 0.11f;
}

// focal(l, t=0) = 0.75 * softplus(l) * sigmoid(l), z = e^l
__device__ __forceinline__ float focal0(float l) {
  float z = __expf(l);
  float r = __builtin_amdgcn_rcpf(1.0f + z);
  float sp = __logf(1.0f + z);
  return 0.75f * sp * (z * r);
}

// focal(l,1) - focal(l,0)
__device__ __forceinline__ float focal_delta(float l) {
  float z = __expf(l);
  float r = __builtin_amdgcn_rcpf(1.0f + z);
  float sp = __logf(1.0f + z);
  return (0.25f * (sp - l)) * r - 0.75f * sp * (z * r);
}

// IoU of prior (cx,cy,w,h as float4) vs target box
__device__ __forceinline__ float iou_pt(float4 pr, const float tbox[4],
                                        float tarea) {
  float px1 = pr.x - 0.5f * pr.z, py1 = pr.y - 0.5f * pr.w;
  float px2 = pr.x + 0.5f * pr.z, py2 = pr.y + 0.5f * pr.w;
  float parea = (px2 - px1) * (py2 - py1);
  float lx = fmaxf(tbox[0], px1);
  float ly = fmaxf(tbox[1], py1);
  float rx = fminf(tbox[2], px2);
  float ry = fminf(tbox[3], py2);
  float iw = fmaxf(rx - lx, 0.0f);
  float ih = fmaxf(ry - ly, 0.0f);
  float inter = iw * ih;
  return inter / (tarea + parea - inter);
}

// ---------------- kernel A: per-target argmax partials ----------------
// grid (MATCH_GX, B). Writes gkeyp[(b*O+t)*MATCH_GX + blockIdx.x] — distinct
// slot per block, plain stores, every slot overwritten every launch. Block
// (0,0) also zeroes acc[0..2]. Coherence: dispatch boundary.

__global__ __launch_bounds__(256)
void match_reduce_kernel(const float4* __restrict__ priors4,
                         const float* __restrict__ targets,
                         unsigned long long* __restrict__ gkeyp,
                         double* __restrict__ acc,
                         int P, int O) {
  int b = blockIdx.y;
  int tid = threadIdx.x;
  int lane = tid & 63, wid = tid >> 6;

  if (blockIdx.x == 0 && b == 0 && tid < 3)
    ((unsigned long long*)acc)[tid] = 0ull;

  __shared__ float s_t[MAX_O][4];
  __shared__ float s_area[MAX_O];
  __shared__ unsigned long long s_key[4][MAX_O];
  if (tid < O) {
    const float* t = targets + ((size_t)b * O + tid) * 5;
    float x1 = t[0], y1 = t[1], x2 = t[2], y2 = t[3];
    s_t[tid][0] = x1; s_t[tid][1] = y1; s_t[tid][2] = x2; s_t[tid][3] = y2;
    s_area[tid] = (x2 - x1) * (y2 - y1);
  }
  __syncthreads();

  float bov[MAX_O];
  unsigned bpi[MAX_O];
#pragma unroll
  for (int t = 0; t < MAX_O; ++t) { bov[t] = -1.0f; bpi[t] = 0u; }

  for (int p = blockIdx.x * blockDim.x + tid; p < P;
       p += MATCH_GX * blockDim.x) {
    float4 pr = priors4[p];
#pragma unroll
    for (int t = 0; t < MAX_O; ++t) {
      if (t < O) {
        float ov = iou_pt(pr, s_t[t], s_area[t]);
        if (ov > bov[t]) { bov[t] = ov; bpi[t] = (unsigned)p; }
      }
    }
  }

#pragma unroll
  for (int t = 0; t < MAX_O; ++t) {
    if (t < O) {
      unsigned long long key = (bov[t] >= 0.0f)
          ? (((unsigned long long)__float_as_uint(bov[t]) << 32) |
             (unsigned long long)(0xFFFFFFFFu - bpi[t]))
          : 0ull;
      for (int o = 32; o > 0; o >>= 1) {
        unsigned long long other = __shfl_xor(key, o, 64);
        if (other > key) key = other;
      }
      if (lane == 0) s_key[wid][t] = key;
    }
  }
  __syncthreads();
  if (tid < O) {
    unsigned long long k0 = s_key[0][tid] > s_key[1][tid] ? s_key[0][tid] : s_key[1][tid];
    unsigned long long k1 = s_key[2][tid] > s_key[3][tid] ? s_key[2][tid] : s_key[3][tid];
    unsigned long long k = k0 > k1 ? k0 : k1;
    gkeyp[((size_t)b * O + tid) * MATCH_GX + blockIdx.x] = k;
  }
}

// ---------------- kernel B: match recompute + loc + conf ----------------
// One block per RPB contiguous rows. Structure:
//   phase 1 (compiler-managed loads): match recompute + loc loss. All
//     compiler vmem loads are issued AND waited here, so the wave's vmcnt
//     ledger is empty when phase 2 starts.
//   phase 2 (inline-asm loads): 20 global_load_dwordx4 issued back-to-back
//     (compiler cannot fission/sink them — round-6 VGPR=60 proved it does
//     from C source), consumed in 2 groups at vmcnt(10)/vmcnt(0), each wait
//     followed by sched_barrier(0) (rule: compiler hoists reg-only ops past
//     inline-asm waitcnt otherwise).

__global__ __launch_bounds__(256, 4)
void loss_kernel(const float4* __restrict__ loc4,
                 const float4* __restrict__ conf4,
                 const float4* __restrict__ priors4,
                 const float* __restrict__ targets,
                 const unsigned long long* __restrict__ gkeyp,
                 double* __restrict__ acc,
                 int P, int O, int BPtot) {
  __shared__ float s_t[MAX_O][4];
  __shared__ float s_area[MAX_O];
  __shared__ int   s_lab[MAX_O];
  __shared__ unsigned s_op[MAX_O];    // override prior index per target
  __shared__ int   s_cls[RPB];
  __shared__ double sbuf_l[4], sbuf_n[4], sbuf_c[4];

  int tid = threadIdx.x;
  int row0 = blockIdx.x * RPB;
  int row = row0 + tid;
  int b = row0 / P;                   // constant per block
  int p = row - b * P;
  int lane = tid & 63, wid = tid >> 6;
  bool full = (row0 + RPB <= BPtot);

  if (tid < O) {
    const float* t = targets + ((size_t)b * O + tid) * 5;
    float x1 = t[0], y1 = t[1], x2 = t[2], y2 = t[3];
    s_t[tid][0] = x1; s_t[tid][1] = y1; s_t[tid][2] = x2; s_t[tid][3] = y2;
    s_area[tid] = (x2 - x1) * (y2 - y1);
    s_lab[tid] = (int)t[4] + 1;
    const unsigned long long* gp = gkeyp + ((size_t)b * O + tid) * MATCH_GX;
    unsigned long long k = gp[0];
#pragma unroll
    for (int i = 1; i < MATCH_GX; ++i) {
      unsigned long long ki = gp[i];
      if (ki > k) k = ki;
    }
    s_op[tid] = 0xFFFFFFFFu - (unsigned)(k & 0xFFFFFFFFull);
  }
  __syncthreads();

  float lsum = 0.0f, nsum = 0.0f, csum = 0.0f;

  if (full) {
    // ---- phase 1: match recompute + loc loss (compiler loads) ----
    float4 pr = priors4[p];
    float4 ld = loc4[row];
    float best = -1.0f;
    int bestt = 0;
#pragma unroll
    for (int t = 0; t < MAX_O; ++t) {
      if (t < O) {
        float ov = iou_pt(pr, s_t[t], s_area[t]);
        if (ov > best) { best = ov; bestt = t; }   // first-max (axis=0 argmax)
      }
    }
#pragma unroll
    for (int t = 0; t < MAX_O; ++t) {              // ascending t: later wins
      if (t < O && s_op[t] == (unsigned)p) { best = 2.0f; bestt = t; }
    }

    int cls;
    if (best >= 0.5f) {
      nsum = 1.0f;
      float x1 = s_t[bestt][0], y1 = s_t[bestt][1];
      float x2 = s_t[bestt][2], y2 = s_t[bestt][3];
      cls = s_lab[bestt];
      float gcx = ((x1 + x2) * 0.5f - pr.x) / (0.1f * pr.z);
      float gcy = ((y1 + y2) * 0.5f - pr.y) / (0.1f * pr.w);
      float gw = __logf((x2 - x1) / pr.z) * 5.0f;   // /0.2
      float gh = __logf((y2 - y1) / pr.w) * 5.0f;
      lsum = bl1f(ld.x - gcx) + bl1f(ld.y - gcy) +
             bl1f(ld.z - gw) + bl1f(ld.w - gh);
    } else {
      cls = (best < 0.4f) ? 0 : -1;
    }
    s_cls[tid] = cls;

    // ---- phase 2: issue all 20 conf loads via inline asm ----
    // voffset = tid*32 + i*8192 (U at offset:0, V at offset:16).
    const char* cbase = (const char*)(conf4 + (size_t)row0 * 20);
    unsigned voff = (unsigned)tid * 32u;
    float4 U[10], V[10];
    __builtin_amdgcn_sched_barrier(0);   // pin: phase-1 loads+waits stay above
#define LDC(i)                                                          \
    asm volatile("global_load_dwordx4 %0, %2, %3 offset:0\n\t"          \
                 "global_load_dwordx4 %1, %2, %3 offset:16"             \
                 : "=v"(U[i]), "=v"(V[i])                               \
                 : "v"(voff + (i) * 8192u), "s"(cbase));
    LDC(0) LDC(1) LDC(2) LDC(3) LDC(4)
    LDC(5) LDC(6) LDC(7) LDC(8) LDC(9)
#undef LDC

    __syncthreads();   // s_cls ready (compiler emits lgkmcnt only — conf
                       // loads stay in flight across the barrier)

#define CONSUME(i)                                                      \
    {                                                                   \
      int ch = tid + ((i) << 8);                                        \
      int rl = ch / 10;                                                 \
      int cc = ch - rl * 10;                                            \
      int rcls = s_cls[rl];                                             \
      float4 u = U[i], v = V[i];                                        \
      float s = focal0(u.x) + focal0(u.y) + focal0(u.z) + focal0(u.w) + \
                focal0(v.x) + focal0(v.y) + focal0(v.z) + focal0(v.w);  \
      if (rcls > 0) {                                                   \
        int j = rcls - 1 - cc * 8;                                      \
        if ((unsigned)j < 8u) {                                         \
          float l = (j < 4)                                             \
              ? (j == 0 ? u.x : j == 1 ? u.y : j == 2 ? u.z : u.w)      \
              : (j == 4 ? v.x : j == 5 ? v.y : j == 6 ? v.z : v.w);     \
          s += focal_delta(l);                                          \
        }                                                               \
      }                                                                 \
      csum += (rcls >= 0) ? s : 0.0f;                                   \
    }

    asm volatile("s_waitcnt vmcnt(10)" ::: "memory");  // loads 0..9 retired
    __builtin_amdgcn_sched_barrier(0);
    CONSUME(0) CONSUME(1) CONSUME(2) CONSUME(3) CONSUME(4)

    asm volatile("s_waitcnt vmcnt(0)" ::: "memory");   // all retired
    __builtin_amdgcn_sched_barrier(0);
    CONSUME(5) CONSUME(6) CONSUME(7) CONSUME(8) CONSUME(9)
#undef CONSUME
  } else {
    // ---- guarded tail path (not hit for the bench shape) ----
    float best = -1.0f;
    int bestt = 0;
    bool valid = row < BPtot;
    if (valid) {
      float4 prt = priors4[p];
#pragma unroll
      for (int t = 0; t < MAX_O; ++t) {
        if (t < O) {
          float ov = iou_pt(prt, s_t[t], s_area[t]);
          if (ov > best) { best = ov; bestt = t; }
        }
      }
#pragma unroll
      for (int t = 0; t < MAX_O; ++t) {
        if (t < O && s_op[t] == (unsigned)p) { best = 2.0f; bestt = t; }
      }
    }
    int cls = -1;
    if (valid) {
      if (best >= 0.5f) {
        nsum = 1.0f;
        float x1 = s_t[bestt][0], y1 = s_t[bestt][1];
        float x2 = s_t[bestt][2], y2 = s_t[bestt][3];
        cls = s_lab[bestt];
        float4 prt = priors4[p];
        float gcx = ((x1 + x2) * 0.5f - prt.x) / (0.1f * prt.z);
        float gcy = ((y1 + y2) * 0.5f - prt.y) / (0.1f * prt.w);
        float gw = __logf((x2 - x1) / prt.z) * 5.0f;
        float gh = __logf((y2 - y1) / prt.w) * 5.0f;
        float4 ldt = loc4[row];
        lsum = bl1f(ldt.x - gcx) + bl1f(ldt.y - gcy) +
               bl1f(ldt.z - gw) + bl1f(ldt.w - gh);
      } else {
        cls = (best < 0.4f) ? 0 : -1;
      }
    }
    s_cls[tid] = cls;
    __syncthreads();
    for (int i = 0; i < 10; ++i) {
      int ch = tid + (i << 8);
      int rl = ch / 10;
      int cc = ch - rl * 10;
      if (row0 + rl < BPtot) {
        int rcls = s_cls[rl];
        const float4* base = conf4 + (size_t)row0 * 20;
        float4 u = base[(size_t)ch * 2];
        float4 v = base[(size_t)ch * 2 + 1];
        float s = focal0(u.x) + focal0(u.y) + focal0(u.z) + focal0(u.w) +
                  focal0(v.x) + focal0(v.y) + focal0(v.z) + focal0(v.w);
        if (rcls > 0) {
          int j = rcls - 1 - cc * 8;
          if ((unsigned)j < 8u) {
            float l = (j < 4) ? (j == 0 ? u.x : j == 1 ? u.y : j == 2 ? u.z : u.w)
                              : (j == 4 ? v.x : j == 5 ? v.y : j == 6 ? v.z : v.w);
            s += focal_delta(l);
          }
        }
        csum += (rcls >= 0) ? s : 0.0f;
      }
    }
  }

  // ---- block reduction, one atomic per accumulator ----
  for (int o = 32; o > 0; o >>= 1) {
    lsum += __shfl_down(lsum, o, 64);
    nsum += __shfl_down(nsum, o, 64);
    csum += __shfl_down(csum, o, 64);
  }
  if (lane == 0) {
    sbuf_l[wid] = (double)lsum;
    sbuf_n[wid] = (double)nsum;
    sbuf_c[wid] = (double)csum;
  }
  __syncthreads();
  if (tid == 0) {
    atomicAdd(&acc[0], sbuf_l[0] + sbuf_l[1] + sbuf_l[2] + sbuf_l[3]);
    atomicAdd(&acc[1], sbuf_c[0] + sbuf_c[1] + sbuf_c[2] + sbuf_c[3]);
    atomicAdd(&acc[2], sbuf_n[0] + sbuf_n[1] + sbuf_n[2] + sbuf_n[3]);
  }
}

// ---------------- kernel C: finalize ----------------

__global__ void final_kernel(const double* __restrict__ acc,
                             float* __restrict__ out) {
  if (threadIdx.x == 0) {
    double pn = acc[2] > 1.0 ? acc[2] : 1.0;
    out[0] = (float)(acc[0] / (pn * 4.0));
    out[1] = (float)(acc[1] / pn);
  }
}

// ---------------- launch ----------------

extern "C" void kernel_launch(void* const* d_in, const int* in_sizes, int n_in,
                              void* d_out, int out_size, void* d_ws, size_t ws_size,
                              hipStream_t stream) {
  const float4* loc4    = (const float4*)d_in[0];
  const float4* conf4   = (const float4*)d_in[1];
  const float4* priors4 = (const float4*)d_in[2];
  const float*  targets = (const float*)d_in[3];
  float* out = (float*)d_out;

  int P  = in_sizes[2] / 4;        // 16384
  int BP = in_sizes[0] / 4;        // B*P
  int B  = BP / P;                 // 32
  int O  = in_sizes[3] / (B * 5);  // 16

  // ws layout: gkeyp (B*O*MATCH_GX u64) | acc (double[3])
  unsigned long long* gkeyp = (unsigned long long*)d_ws;
  double* acc = (double*)((char*)d_ws + (size_t)B * O * MATCH_GX * 8);

  hipLaunchKernelGGL(match_reduce_kernel, dim3(MATCH_GX, B), dim3(256), 0,
                     stream, priors4, targets, gkeyp, acc, P, O);

  int nblk = (BP + RPB - 1) / RPB;   // 2048
  hipLaunchKernelGGL(loss_kernel, dim3(nblk), dim3(256), 0, stream,
                     loc4, conf4, priors4, targets, gkeyp, acc, P, O, BP);

  hipLaunchKernelGGL(final_kernel, dim3(1), dim3(64), 0, stream, acc, out);
}

// Round 8
// 289.830 us; speedup vs baseline: 1.0128x; 1.0128x over previous
//
#include <hip/hip_runtime.h>

#define MAX_O 16
#define RPB 256      // rows per block in the loss kernel (== blockDim.x)
#define MATCH_GX 32  // prior-chunk blocks per batch in the match kernel

// ---------------- device helpers ----------------

// balanced_l1: R_ALPHA=0.5, R_GAMMA=1.5, R_BETA=0.11, b = e^3 - 1
__device__ __forceinline__ float bl1f(float diff) {
  const float bc = 19.085537f;  // float32(e^3 - 1)
  float d = fabsf(diff);
  if (d < 0.11f) {
    return 0.5f / bc * (bc * d + 1.0f) * __logf(1.0f + bc * d / 0.11f) - 0.5f * d;
  }
  return 1.5f * d + 1.5f / bc - 0.5f * 0.11f;
}

// focal(l, t=0) = 0.75 * softplus(l) * sigmoid(l), z = e^l
__device__ __forceinline__ float focal0(float l) {
  float z = __expf(l);
  float r = __builtin_amdgcn_rcpf(1.0f + z);
  float sp = __logf(1.0f + z);
  return 0.75f * sp * (z * r);
}

// focal(l,1) - focal(l,0)
__device__ __forceinline__ float focal_delta(float l) {
  float z = __expf(l);
  float r = __builtin_amdgcn_rcpf(1.0f + z);
  float sp = __logf(1.0f + z);
  return (0.25f * (sp - l)) * r - 0.75f * sp * (z * r);
}

// IoU of prior (cx,cy,w,h as float4) vs target box
__device__ __forceinline__ float iou_pt(float4 pr, const float tbox[4],
                                        float tarea) {
  float px1 = pr.x - 0.5f * pr.z, py1 = pr.y - 0.5f * pr.w;
  float px2 = pr.x + 0.5f * pr.z, py2 = pr.y + 0.5f * pr.w;
  float parea = (px2 - px1) * (py2 - py1);
  float lx = fmaxf(tbox[0], px1);
  float ly = fmaxf(tbox[1], py1);
  float rx = fminf(tbox[2], px2);
  float ry = fminf(tbox[3], py2);
  float iw = fmaxf(rx - lx, 0.0f);
  float ih = fmaxf(ry - ly, 0.0f);
  float inter = iw * ih;
  return inter / (tarea + parea - inter);
}

// ---------------- kernel A: per-target argmax partials ----------------

__global__ __launch_bounds__(256)
void match_reduce_kernel(const float4* __restrict__ priors4,
                         const float* __restrict__ targets,
                         unsigned long long* __restrict__ gkeyp,
                         double* __restrict__ acc,
                         int P, int O) {
  int b = blockIdx.y;
  int tid = threadIdx.x;
  int lane = tid & 63, wid = tid >> 6;

  if (blockIdx.x == 0 && b == 0 && tid < 3)
    ((unsigned long long*)acc)[tid] = 0ull;

  __shared__ float s_t[MAX_O][4];
  __shared__ float s_area[MAX_O];
  __shared__ unsigned long long s_key[4][MAX_O];
  if (tid < O) {
    const float* t = targets + ((size_t)b * O + tid) * 5;
    float x1 = t[0], y1 = t[1], x2 = t[2], y2 = t[3];
    s_t[tid][0] = x1; s_t[tid][1] = y1; s_t[tid][2] = x2; s_t[tid][3] = y2;
    s_area[tid] = (x2 - x1) * (y2 - y1);
  }
  __syncthreads();

  float bov[MAX_O];
  unsigned bpi[MAX_O];
#pragma unroll
  for (int t = 0; t < MAX_O; ++t) { bov[t] = -1.0f; bpi[t] = 0u; }

  for (int p = blockIdx.x * blockDim.x + tid; p < P;
       p += MATCH_GX * blockDim.x) {
    float4 pr = priors4[p];
#pragma unroll
    for (int t = 0; t < MAX_O; ++t) {
      if (t < O) {
        float ov = iou_pt(pr, s_t[t], s_area[t]);
        if (ov > bov[t]) { bov[t] = ov; bpi[t] = (unsigned)p; }
      }
    }
  }

#pragma unroll
  for (int t = 0; t < MAX_O; ++t) {
    if (t < O) {
      unsigned long long key = (bov[t] >= 0.0f)
          ? (((unsigned long long)__float_as_uint(bov[t]) << 32) |
             (unsigned long long)(0xFFFFFFFFu - bpi[t]))
          : 0ull;
      for (int o = 32; o > 0; o >>= 1) {
        unsigned long long other = __shfl_xor(key, o, 64);
        if (other > key) key = other;
      }
      if (lane == 0) s_key[wid][t] = key;
    }
  }
  __syncthreads();
  if (tid < O) {
    unsigned long long k0 = s_key[0][tid] > s_key[1][tid] ? s_key[0][tid] : s_key[1][tid];
    unsigned long long k1 = s_key[2][tid] > s_key[3][tid] ? s_key[2][tid] : s_key[3][tid];
    unsigned long long k = k0 > k1 ? k0 : k1;
    gkeyp[((size_t)b * O + tid) * MATCH_GX + blockIdx.x] = k;
  }
}

// ---------------- kernel B: match recompute + loc + conf ----------------
// Corrected T14/asm structure (r7 got the order wrong):
//   phase 0: targets + gkeyp -> LDS (compiler loads, fully drained), barrier.
//   ISSUE: 22 asm loads back-to-back (priors, loc, 20x conf dwordx4).
//   vmcnt(20): priors/loc landed; 20 conf loads STAY IN FLIGHT while the
//     match-recompute + loc-loss math runs (~1000 cy of real work).
//   barrier (lgkmcnt only - conf loads cross it), prefetch all 10 s_cls
//     values to registers (no LDS reads left in consume).
//   vmcnt(10) -> consume chunks 0-4; vmcnt(0) -> consume 5-9.
// Waitcnts carry NO "memory" clobber (r7 lesson: it forces LDS re-reads);
// ordering is pinned by sched_barrier(0) per guide rule #18.

__global__ __launch_bounds__(256, 4)
void loss_kernel(const float4* __restrict__ loc4,
                 const float4* __restrict__ conf4,
                 const float4* __restrict__ priors4,
                 const float* __restrict__ targets,
                 const unsigned long long* __restrict__ gkeyp,
                 double* __restrict__ acc,
                 int P, int O, int BPtot) {
  __shared__ float s_t[MAX_O][4];
  __shared__ float s_area[MAX_O];
  __shared__ int   s_lab[MAX_O];
  __shared__ unsigned s_op[MAX_O];    // override prior index per target
  __shared__ int   s_cls[RPB];
  __shared__ double sbuf_l[4], sbuf_n[4], sbuf_c[4];

  int tid = threadIdx.x;
  int row0 = blockIdx.x * RPB;
  int row = row0 + tid;
  int b = row0 / P;                   // constant per block
  int p = row - b * P;
  int lane = tid & 63, wid = tid >> 6;
  bool full = (row0 + RPB <= BPtot);

  // ---- phase 0: targets + override table into LDS (small, drained) ----
  if (tid < O) {
    const float* t = targets + ((size_t)b * O + tid) * 5;
    float x1 = t[0], y1 = t[1], x2 = t[2], y2 = t[3];
    s_t[tid][0] = x1; s_t[tid][1] = y1; s_t[tid][2] = x2; s_t[tid][3] = y2;
    s_area[tid] = (x2 - x1) * (y2 - y1);
    s_lab[tid] = (int)t[4] + 1;
    const unsigned long long* gp = gkeyp + ((size_t)b * O + tid) * MATCH_GX;
    unsigned long long k = gp[0];
#pragma unroll
    for (int i = 1; i < MATCH_GX; ++i) {
      unsigned long long ki = gp[i];
      if (ki > k) k = ki;
    }
    s_op[tid] = 0xFFFFFFFFu - (unsigned)(k & 0xFFFFFFFFull);
  }
  __syncthreads();

  float lsum = 0.0f, nsum = 0.0f, csum = 0.0f;

  if (full) {
    // ---- ISSUE all 22 loads via inline asm, back-to-back ----
    float4 pr, ld;
    float4 U[10], V[10];
    {
      unsigned voff_p = (unsigned)p * 16u;
      unsigned voff_l = (unsigned)row * 16u;
      const char* pbase_c = (const char*)priors4;
      const char* lbase_c = (const char*)loc4;
      const char* cbase   = (const char*)(conf4 + (size_t)row0 * 20);
      unsigned voff = (unsigned)tid * 32u;
      __builtin_amdgcn_sched_barrier(0);
      asm volatile("global_load_dwordx4 %0, %1, %2 offset:0"
                   : "=v"(pr) : "v"(voff_p), "s"(pbase_c));
      asm volatile("global_load_dwordx4 %0, %1, %2 offset:0"
                   : "=v"(ld) : "v"(voff_l), "s"(lbase_c));
#define LDC(i)                                                          \
      asm volatile("global_load_dwordx4 %0, %2, %3 offset:0\n\t"        \
                   "global_load_dwordx4 %1, %2, %3 offset:16"           \
                   : "=v"(U[i]), "=v"(V[i])                             \
                   : "v"(voff + (i) * 8192u), "s"(cbase));
      LDC(0) LDC(1) LDC(2) LDC(3) LDC(4)
      LDC(5) LDC(6) LDC(7) LDC(8) LDC(9)
#undef LDC
    }

    // ---- wait only for priors+loc; 20 conf loads remain in flight ----
    asm volatile("s_waitcnt vmcnt(20)");
    __builtin_amdgcn_sched_barrier(0);

    // ---- phase 1: match recompute + loc loss (under in-flight loads) ----
    float best = -1.0f;
    int bestt = 0;
#pragma unroll
    for (int t = 0; t < MAX_O; ++t) {
      if (t < O) {
        float ov = iou_pt(pr, s_t[t], s_area[t]);
        if (ov > best) { best = ov; bestt = t; }   // first-max (axis=0 argmax)
      }
    }
#pragma unroll
    for (int t = 0; t < MAX_O; ++t) {              // ascending t: later wins
      if (t < O && s_op[t] == (unsigned)p) { best = 2.0f; bestt = t; }
    }

    int cls;
    if (best >= 0.5f) {
      nsum = 1.0f;
      float x1 = s_t[bestt][0], y1 = s_t[bestt][1];
      float x2 = s_t[bestt][2], y2 = s_t[bestt][3];
      cls = s_lab[bestt];
      float gcx = ((x1 + x2) * 0.5f - pr.x) / (0.1f * pr.z);
      float gcy = ((y1 + y2) * 0.5f - pr.y) / (0.1f * pr.w);
      float gw = __logf((x2 - x1) / pr.z) * 5.0f;   // /0.2
      float gh = __logf((y2 - y1) / pr.w) * 5.0f;
      lsum = bl1f(ld.x - gcx) + bl1f(ld.y - gcy) +
             bl1f(ld.z - gw) + bl1f(ld.w - gh);
    } else {
      cls = (best < 0.4f) ? 0 : -1;
    }
    s_cls[tid] = cls;
    __syncthreads();           // lgkmcnt drain only; conf stays in flight

    // ---- prefetch all 10 row-classes to registers (no LDS in consume) ----
    int rcls[10], ccv[10];
#pragma unroll
    for (int i = 0; i < 10; ++i) {
      int ch = tid + (i << 8);
      int rl = ch / 10;        // magic-mul
      ccv[i] = ch - rl * 10;
      rcls[i] = s_cls[rl];
    }
    asm volatile("" :: "v"(rcls[0]), "v"(rcls[1]), "v"(rcls[2]),
                       "v"(rcls[3]), "v"(rcls[4]), "v"(rcls[5]),
                       "v"(rcls[6]), "v"(rcls[7]), "v"(rcls[8]),
                       "v"(rcls[9]));   // pin: ds_reads issued before vm wait

#define CONSUME(i)                                                      \
    {                                                                   \
      int rc = rcls[i];                                                 \
      int cc = ccv[i];                                                  \
      float4 u = U[i], v = V[i];                                        \
      float s = focal0(u.x) + focal0(u.y) + focal0(u.z) + focal0(u.w) + \
                focal0(v.x) + focal0(v.y) + focal0(v.z) + focal0(v.w);  \
      if (rc > 0) {                                                     \
        int j = rc - 1 - cc * 8;                                        \
        if ((unsigned)j < 8u) {                                         \
          float l = (j < 4)                                             \
              ? (j == 0 ? u.x : j == 1 ? u.y : j == 2 ? u.z : u.w)      \
              : (j == 4 ? v.x : j == 5 ? v.y : j == 6 ? v.z : v.w);     \
          s += focal_delta(l);                                          \
        }                                                               \
      }                                                                 \
      csum += (rc >= 0) ? s : 0.0f;                                     \
    }

    asm volatile("s_waitcnt vmcnt(10)");   // chunks 0..4 retired
    __builtin_amdgcn_sched_barrier(0);
    CONSUME(0) CONSUME(1) CONSUME(2) CONSUME(3) CONSUME(4)

    asm volatile("s_waitcnt vmcnt(0)");    // all retired
    __builtin_amdgcn_sched_barrier(0);
    CONSUME(5) CONSUME(6) CONSUME(7) CONSUME(8) CONSUME(9)
#undef CONSUME
  } else {
    // ---- guarded tail path (not hit for the bench shape) ----
    float best = -1.0f;
    int bestt = 0;
    bool valid = row < BPtot;
    if (valid) {
      float4 prt = priors4[p];
#pragma unroll
      for (int t = 0; t < MAX_O; ++t) {
        if (t < O) {
          float ov = iou_pt(prt, s_t[t], s_area[t]);
          if (ov > best) { best = ov; bestt = t; }
        }
      }
#pragma unroll
      for (int t = 0; t < MAX_O; ++t) {
        if (t < O && s_op[t] == (unsigned)p) { best = 2.0f; bestt = t; }
      }
    }
    int cls = -1;
    if (valid) {
      if (best >= 0.5f) {
        nsum = 1.0f;
        float x1 = s_t[bestt][0], y1 = s_t[bestt][1];
        float x2 = s_t[bestt][2], y2 = s_t[bestt][3];
        cls = s_lab[bestt];
        float4 prt = priors4[p];
        float gcx = ((x1 + x2) * 0.5f - prt.x) / (0.1f * prt.z);
        float gcy = ((y1 + y2) * 0.5f - prt.y) / (0.1f * prt.w);
        float gw = __logf((x2 - x1) / prt.z) * 5.0f;
        float gh = __logf((y2 - y1) / prt.w) * 5.0f;
        float4 ldt = loc4[row];
        lsum = bl1f(ldt.x - gcx) + bl1f(ldt.y - gcy) +
               bl1f(ldt.z - gw) + bl1f(ldt.w - gh);
      } else {
        cls = (best < 0.4f) ? 0 : -1;
      }
    }
    s_cls[tid] = cls;
    __syncthreads();
    for (int i = 0; i < 10; ++i) {
      int ch = tid + (i << 8);
      int rl = ch / 10;
      int cc = ch - rl * 10;
      if (row0 + rl < BPtot) {
        int rc = s_cls[rl];
        const float4* base = conf4 + (size_t)row0 * 20;
        float4 u = base[(size_t)ch * 2];
        float4 v = base[(size_t)ch * 2 + 1];
        float s = focal0(u.x) + focal0(u.y) + focal0(u.z) + focal0(u.w) +
                  focal0(v.x) + focal0(v.y) + focal0(v.z) + focal0(v.w);
        if (rc > 0) {
          int j = rc - 1 - cc * 8;
          if ((unsigned)j < 8u) {
            float l = (j < 4) ? (j == 0 ? u.x : j == 1 ? u.y : j == 2 ? u.z : u.w)
                              : (j == 4 ? v.x : j == 5 ? v.y : j == 6 ? v.z : v.w);
            s += focal_delta(l);
          }
        }
        csum += (rc >= 0) ? s : 0.0f;
      }
    }
  }

  // ---- block reduction, one atomic per accumulator ----
  for (int o = 32; o > 0; o >>= 1) {
    lsum += __shfl_down(lsum, o, 64);
    nsum += __shfl_down(nsum, o, 64);
    csum += __shfl_down(csum, o, 64);
  }
  if (lane == 0) {
    sbuf_l[wid] = (double)lsum;
    sbuf_n[wid] = (double)nsum;
    sbuf_c[wid] = (double)csum;
  }
  __syncthreads();
  if (tid == 0) {
    atomicAdd(&acc[0], sbuf_l[0] + sbuf_l[1] + sbuf_l[2] + sbuf_l[3]);
    atomicAdd(&acc[1], sbuf_c[0] + sbuf_c[1] + sbuf_c[2] + sbuf_c[3]);
    atomicAdd(&acc[2], sbuf_n[0] + sbuf_n[1] + sbuf_n[2] + sbuf_n[3]);
  }
}

// ---------------- kernel C: finalize ----------------

__global__ void final_kernel(const double* __restrict__ acc,
                             float* __restrict__ out) {
  if (threadIdx.x == 0) {
    double pn = acc[2] > 1.0 ? acc[2] : 1.0;
    out[0] = (float)(acc[0] / (pn * 4.0));
    out[1] = (float)(acc[1] / pn);
  }
}

// ---------------- launch ----------------

extern "C" void kernel_launch(void* const* d_in, const int* in_sizes, int n_in,
                              void* d_out, int out_size, void* d_ws, size_t ws_size,
                              hipStream_t stream) {
  const float4* loc4    = (const float4*)d_in[0];
  const float4* conf4   = (const float4*)d_in[1];
  const float4* priors4 = (const float4*)d_in[2];
  const float*  targets = (const float*)d_in[3];
  float* out = (float*)d_out;

  int P  = in_sizes[2] / 4;        // 16384
  int BP = in_sizes[0] / 4;        // B*P
  int B  = BP / P;                 // 32
  int O  = in_sizes[3] / (B * 5);  // 16

  // ws layout: gkeyp (B*O*MATCH_GX u64) | acc (double[3])
  unsigned long long* gkeyp = (unsigned long long*)d_ws;
  double* acc = (double*)((char*)d_ws + (size_t)B * O * MATCH_GX * 8);

  hipLaunchKernelGGL(match_reduce_kernel, dim3(MATCH_GX, B), dim3(256), 0,
                     stream, priors4, targets, gkeyp, acc, P, O);

  int nblk = (BP + RPB - 1) / RPB;   // 2048
  hipLaunchKernelGGL(loss_kernel, dim3(nblk), dim3(256), 0, stream,
                     loc4, conf4, priors4, targets, gkeyp, acc, P, O, BP);

  hipLaunchKernelGGL(final_kernel, dim3(1), dim3(64), 0, stream, acc, out);
}